// Round 12
// baseline (1709.830 us; speedup 1.0000x reference)
//
#include <hip/hip_runtime.h>
#include <math.h>
#include <stdint.h>

#define SEQ    512
#define BATCH  64
#define IN_    64
#define HID    512
#define MID    256
#define CONCAT 1088
#define ZS     320
#define NW     4      // weight quarters (WGs per batch)
#define QZ     64     // MID/NW: z_mid rows per WG
#define L2E    1.4426950408889634f

typedef _Float16 h2t __attribute__((ext_vector_type(2)));

__device__ __forceinline__ float fdot2u(uint32_t a, uint32_t b, float c) {
    return __builtin_amdgcn_fdot2(__builtin_bit_cast(h2t, a),
                                  __builtin_bit_cast(h2t, b), c, false);
}
__device__ __forceinline__ uint32_t packrtn(float a, float b) {
    h2t h = { (_Float16)a, (_Float16)b };
    return __builtin_bit_cast(uint32_t, h);
}
template <int CTRL>
__device__ __forceinline__ float dpp_add(float v) {
    int o = __builtin_amdgcn_update_dpp(0, __builtin_bit_cast(int, v), CTRL, 0xF, 0xF, true);
    return v + __builtin_bit_cast(float, o);
}
template <int CTRL>
__device__ __forceinline__ float dpp_get(float v) {   // fetch lane-permuted value
    int o = __builtin_amdgcn_update_dpp(0, __builtin_bit_cast(int, v), CTRL, 0xF, 0xF, true);
    return __builtin_bit_cast(float, o);
}
__device__ __forceinline__ float red16(float v) {     // sum over 16-lane DPP row
    v = dpp_add<0xB1>(v);   // quad_perm xor1
    v = dpp_add<0x4E>(v);   // quad_perm xor2
    v = dpp_add<0x124>(v);  // row_ror:4
    v = dpp_add<0x128>(v);  // row_ror:8
    return v;
}
__device__ __forceinline__ float sw_add16(float v) {  // += lane^16 value
    int o = __builtin_amdgcn_ds_swizzle(__builtin_bit_cast(int, v), 0x401F);
    return v + __builtin_bit_cast(float, o);
}
__device__ __forceinline__ float fexp2(float x) {
    float r;
    asm("v_exp_f32 %0, %1" : "=v"(r) : "v"(x));
    return r;
}
__device__ __forceinline__ float frcp(float x) { return __builtin_amdgcn_rcpf(x); }
__device__ __forceinline__ float fsigmoid(float x) { return frcp(1.f + fexp2(-x * L2E)); }
__device__ __forceinline__ float ftanh(float x) { return 1.f - 2.f * frcp(fexp2(x * (2.f * L2E)) + 1.f); }
// zin: 32 chunks x 17 u32, padded to 20 (80B, 16B-aligned chunk base)
__device__ __forceinline__ int zidx(int k) { return (k / 17) * 20 + (k % 17); }

// Stamped exchange: [BATCH][2(parity)][NW][HID] u64. hi32 = stamp (t+1),
// lo32 = packed fp16 (s-partial, m-partial). 8B atomic word => data is
// self-validating; relaxed suffices. Never reset (replay-safe: stale words
// from a previous replay are bit-identical; first call sees zero stamps).
__device__ uint64_t g_px[(size_t)BATCH * 2 * NW * HID];

// Round-8 structure (best-known: 1041us), with the explicit post-store
// vmcnt(0) drain REMOVED: vmcnt retires in issue order, so issuing the px
// store first and the 3 poll loads (different addresses) right after
// guarantees the store completes no later than the first poll data arrives.
// Store can't starve behind polls: it's ahead in the per-wave FIFO and poll
// RETRIES are s_sleep-throttled (round-6's storm had no backoff).
__global__ __launch_bounds__(512, 1)
void metamu13_kernel(const float* __restrict__ x,      // [SEQ][BATCH][IN_]
                     const float* __restrict__ old_m,  // [BATCH][HID]
                     const float* __restrict__ old_s,  // [BATCH][HID]
                     const float* __restrict__ W_z,    // [MID][CONCAT]
                     const float* __restrict__ b_z,
                     const float* __restrict__ W_s,    // [HID][ZS]
                     const float* __restrict__ b_s,
                     const float* __restrict__ W_m,    // [HID][ZS]
                     const float* __restrict__ b_m,
                     float* __restrict__ out)
{
    const int bid = blockIdx.x;
    const int b   = bid & 63;      // batch
    const int w   = bid >> 6;      // weight quarter; {b, b+64, ...} same XCD
    const int tid = threadIdx.x;
    const int h   = tid;           // finish/px row (global h)

    __shared__ __align__(16) uint32_t zin2[2][32 * 20]; // [x|m|1/s] fp16 pairs
    __shared__ __align__(16) uint32_t zvec2[2][40];     // [x-slice(8)|z-quarter(32)]

    const int g2 = tid >> 5, c2 = tid & 31;   // phase A: 4-row group, K-chunk
    const int l  = tid & 1;                    // phase B: column-half

    // ---- one-time: weights -> VGPRs (fp16 RTN) ----
    uint32_t wA[4][17];
    #pragma unroll
    for (int r = 0; r < 4; ++r) {
        const float* p = W_z + (size_t)(QZ * w + 4 * g2 + r) * CONCAT + 34 * c2;
        #pragma unroll
        for (int i = 0; i < 17; ++i) {
            float2 a = *reinterpret_cast<const float2*>(p + 2 * i);
            wA[r][i] = packrtn(a.x, a.y);
        }
    }
    // phase-B: rows h0=tid&~1, h1=tid|1; col-half l of {x 16w..+16} U {z 64w..+64}
    uint32_t wS0[20], wM0[20], wS1[20], wM1[20];
    {
        const int h0 = tid & ~1, h1 = tid | 1;
        const float* ps0 = W_s + (size_t)h0 * ZS;
        const float* pm0 = W_m + (size_t)h0 * ZS;
        const float* ps1 = W_s + (size_t)h1 * ZS;
        const float* pm1 = W_m + (size_t)h1 * ZS;
        #pragma unroll
        for (int i = 0; i < 4; ++i) {   // x cols: 16w + 8l + 2i
            const int o = 16 * w + 8 * l + 2 * i;
            float2 a0 = *reinterpret_cast<const float2*>(ps0 + o);
            float2 b0 = *reinterpret_cast<const float2*>(pm0 + o);
            float2 a1 = *reinterpret_cast<const float2*>(ps1 + o);
            float2 b1 = *reinterpret_cast<const float2*>(pm1 + o);
            wS0[i] = packrtn(a0.x, a0.y); wM0[i] = packrtn(b0.x, b0.y);
            wS1[i] = packrtn(a1.x, a1.y); wM1[i] = packrtn(b1.x, b1.y);
        }
        #pragma unroll
        for (int i = 0; i < 16; ++i) {  // z cols: 64 + 64w + 32l + 2i
            const int o = 64 + 64 * w + 32 * l + 2 * i;
            float2 a0 = *reinterpret_cast<const float2*>(ps0 + o);
            float2 b0 = *reinterpret_cast<const float2*>(pm0 + o);
            float2 a1 = *reinterpret_cast<const float2*>(ps1 + o);
            float2 b1 = *reinterpret_cast<const float2*>(pm1 + o);
            wS0[4 + i] = packrtn(a0.x, a0.y); wM0[4 + i] = packrtn(b0.x, b0.y);
            wS1[4 + i] = packrtn(a1.x, a1.y); wM1[4 + i] = packrtn(b1.x, b1.y);
        }
    }
    float bz[4];
    #pragma unroll
    for (int r = 0; r < 4; ++r) bz[r] = b_z[QZ * w + 4 * g2 + r];
    const float bsv = b_s[h], bmv = b_m[h];

    // ---- registers: full per-h state (redundant across the 4 WGs) ----
    float sreg = old_s[b * HID + h];
    float mreg = old_m[b * HID + h];

    // x prefetch: threads 0..31 hold float pair (2*tid, 2*tid+1)
    float2 xv = {0.f, 0.f};
    if (tid < 32) xv = *reinterpret_cast<const float2*>(x + (size_t)b * IN_ + 2 * tid);

    // ---- initial staging of zin[0](t=0) and zvec[0] x-slice ----
    if (tid < 256) {
        float2 mv = *reinterpret_cast<const float2*>(old_m + b * HID + 2 * tid);
        zin2[0][zidx(32 + tid)] = packrtn(mv.x, mv.y);
    } else {
        const int j = tid - 256;
        float2 sv = *reinterpret_cast<const float2*>(old_s + b * HID + 2 * j);
        zin2[0][zidx(288 + j)] = packrtn(frcp(sv.x), frcp(sv.y));
    }
    if (tid < 32) zin2[0][zidx(tid)] = packrtn(xv.x, xv.y);
    if (tid >= 8 * w && tid < 8 * w + 8) zvec2[0][tid - 8 * w] = packrtn(xv.x, xv.y);
    __syncthreads();

    float* __restrict__ out_m = out;
    float* __restrict__ out_s = out + (size_t)SEQ * BATCH * HID;

    for (int t = 0; t < SEQ; ++t) {
        const int par = t & 1;
        const int np  = par ^ 1;
        const uint64_t want = (uint64_t)(t + 1);

        // ---- phase A: z_mid rows 4g2..4g2+3, K split over 32 lanes ----
        {
            uint32_t zf[17];
            const uint32_t* zc = &zin2[par][c2 * 20];
            #pragma unroll
            for (int i = 0; i < 4; ++i) {
                uint4 v = *reinterpret_cast<const uint4*>(zc + 4 * i);
                zf[4 * i] = v.x; zf[4 * i + 1] = v.y; zf[4 * i + 2] = v.z; zf[4 * i + 3] = v.w;
            }
            zf[16] = zc[16];
            float a0 = 0.f, a1 = 0.f, a2 = 0.f, a3 = 0.f;
            #pragma unroll
            for (int i = 0; i < 17; ++i) {
                a0 = fdot2u(wA[0][i], zf[i], a0);
                a1 = fdot2u(wA[1][i], zf[i], a1);
                a2 = fdot2u(wA[2][i], zf[i], a2);
                a3 = fdot2u(wA[3][i], zf[i], a3);
            }
            a0 = sw_add16(red16(a0));
            a1 = sw_add16(red16(a1));
            a2 = sw_add16(red16(a2));
            a3 = sw_add16(red16(a3));
            if (c2 == 0) {
                zvec2[par][8 + 2 * g2]     = packrtn(ftanh(a0 + bz[0]), ftanh(a1 + bz[1]));
                zvec2[par][8 + 2 * g2 + 1] = packrtn(ftanh(a2 + bz[2]), ftanh(a3 + bz[3]));
            }
        }
        __syncthreads();   // zvec z-quarter visible to phase B

        // ---- phase B: rows (tid&~1, tid|1) x col-half l; xor1 -> full sums ----
        float as, am;
        {
            uint32_t zg[20];
            {
                uint4 v = *reinterpret_cast<const uint4*>(&zvec2[par][4 * l]);
                zg[0] = v.x; zg[1] = v.y; zg[2] = v.z; zg[3] = v.w;
            }
            const uint32_t* zc2 = &zvec2[par][8 + 16 * l];
            #pragma unroll
            for (int i = 0; i < 4; ++i) {
                uint4 v = *reinterpret_cast<const uint4*>(zc2 + 4 * i);
                zg[4 + 4 * i] = v.x; zg[5 + 4 * i] = v.y; zg[6 + 4 * i] = v.z; zg[7 + 4 * i] = v.w;
            }
            float as0 = 0.f, am0 = 0.f, as1 = 0.f, am1 = 0.f;
            #pragma unroll
            for (int i = 0; i < 20; ++i) {
                as0 = fdot2u(wS0[i], zg[i], as0);
                am0 = fdot2u(wM0[i], zg[i], am0);
                as1 = fdot2u(wS1[i], zg[i], as1);
                am1 = fdot2u(wM1[i], zg[i], am1);
            }
            as0 = dpp_add<0xB1>(as0);   // + other column-half (lane^1)
            am0 = dpp_add<0xB1>(am0);
            as1 = dpp_add<0xB1>(as1);
            am1 = dpp_add<0xB1>(am1);
            as = l ? as1 : as0;          // full per-WG partial for row h = tid
            am = l ? am1 : am0;
        }
        // publish stamped word {t+1, packed partials}. NO vmcnt drain: the
        // store is issued ahead of the poll loads (compiler barrier pins
        // program order); in-order vmcnt retirement means the store is done
        // no later than the first poll load's data arrives.
        __hip_atomic_store(&g_px[(((size_t)b * 2 + par) * NW + w) * HID + h],
                           (want << 32) | (uint64_t)packrtn(as, am),
                           __ATOMIC_RELAXED, __HIP_MEMORY_SCOPE_AGENT);
        asm volatile("" ::: "memory");   // compile-time order pin only

        // ---- poll 3 peers' stamped words CONCURRENTLY (sleep on retry) ----
        {
            const size_t base = ((size_t)b * 2 + par) * NW;
            const uint64_t* s0 = &g_px[(base + ((w + 1) & 3)) * HID + h];
            const uint64_t* s1 = &g_px[(base + ((w + 2) & 3)) * HID + h];
            const uint64_t* s2 = &g_px[(base + ((w + 3) & 3)) * HID + h];
            uint64_t p0 = __hip_atomic_load(s0, __ATOMIC_RELAXED, __HIP_MEMORY_SCOPE_AGENT);
            uint64_t p1 = __hip_atomic_load(s1, __ATOMIC_RELAXED, __HIP_MEMORY_SCOPE_AGENT);
            uint64_t p2 = __hip_atomic_load(s2, __ATOMIC_RELAXED, __HIP_MEMORY_SCOPE_AGENT);

            // x prefetch for t+1 issues while the first poll loads fly
            if (tid < 32 && t + 1 < SEQ)
                xv = *reinterpret_cast<const float2*>(
                    x + ((size_t)(t + 1) * BATCH + b) * IN_ + 2 * tid);

            bool r0 = (p0 >> 32) == want;
            bool r1 = (p1 >> 32) == want;
            bool r2 = (p2 >> 32) == want;
            while (!(r0 && r1 && r2)) {
                __builtin_amdgcn_s_sleep(1);   // back off: don't starve stores
                if (!r0) { p0 = __hip_atomic_load(s0, __ATOMIC_RELAXED, __HIP_MEMORY_SCOPE_AGENT); }
                if (!r1) { p1 = __hip_atomic_load(s1, __ATOMIC_RELAXED, __HIP_MEMORY_SCOPE_AGENT); }
                if (!r2) { p2 = __hip_atomic_load(s2, __ATOMIC_RELAXED, __HIP_MEMORY_SCOPE_AGENT); }
                r0 = (p0 >> 32) == want;
                r1 = (p1 >> 32) == want;
                r2 = (p2 >> 32) == want;
            }
            h2t h0 = __builtin_bit_cast(h2t, (uint32_t)p0);
            h2t h1 = __builtin_bit_cast(h2t, (uint32_t)p1);
            h2t h2 = __builtin_bit_cast(h2t, (uint32_t)p2);
            as += (float)h0.x + (float)h1.x + (float)h2.x;
            am += (float)h0.y + (float)h1.y + (float)h2.y;
        }

        // ---- finish: state update for row h (redundant in all 4 WGs) ----
        const float sig  = fsigmoid(as + bsv);
        const float ns   = sreg + sig;
        const float inv  = frcp(ns);
        const float gate = sreg * inv;             // stop-grad: old_s / new_s
        const float nm   = gate * mreg + (1.f - gate) * ftanh(am + bmv);
        sreg = ns; mreg = nm;

        // owner WG writes output for its h-quarter
        if ((h >> 7) == w) {
            const size_t o = ((size_t)t * BATCH + b) * HID + h;
            out_m[o] = nm;
            out_s[o] = ns;
        }

        // ---- stage zin[np](t+1) + zvec[np] x-slice (DPP pair swap) ----
        const float nm_n  = dpp_get<0xB1>(nm);     // neighbor lane^1 value
        const float inv_n = dpp_get<0xB1>(inv);
        if ((tid & 1) == 0) {
            zin2[np][zidx(32 + (tid >> 1))]  = packrtn(nm, nm_n);
            zin2[np][zidx(288 + (tid >> 1))] = packrtn(inv, inv_n);
        }
        if (t + 1 < SEQ) {
            if (tid < 32) zin2[np][zidx(tid)] = packrtn(xv.x, xv.y);
            if (tid >= 8 * w && tid < 8 * w + 8)
                zvec2[np][tid - 8 * w] = packrtn(xv.x, xv.y);
        }
        __syncthreads();   // staging stable before next phase A
    }
}

extern "C" void kernel_launch(void* const* d_in, const int* in_sizes, int n_in,
                              void* d_out, int out_size, void* d_ws, size_t ws_size,
                              hipStream_t stream) {
    const float* x     = (const float*)d_in[0];
    const float* old_m = (const float*)d_in[1];
    const float* old_s = (const float*)d_in[2];
    const float* W_z   = (const float*)d_in[3];
    const float* b_z   = (const float*)d_in[4];
    const float* W_s   = (const float*)d_in[5];
    const float* b_s   = (const float*)d_in[6];
    const float* W_m   = (const float*)d_in[7];
    const float* b_m   = (const float*)d_in[8];

    metamu13_kernel<<<dim3(BATCH * NW), dim3(512), 0, stream>>>(
        x, old_m, old_s, W_z, b_z, W_s, b_s, W_m, b_m, (float*)d_out);
}

// Round 13
// 1112.406 us; speedup vs baseline: 1.5371x; 1.5371x over previous
//
#include <hip/hip_runtime.h>
#include <math.h>
#include <stdint.h>

#define SEQ    512
#define BATCH  64
#define IN_    64
#define HID    512
#define MID    256
#define CONCAT 1088
#define ZS     320
#define NW     4      // weight quarters (WGs per batch)
#define QZ     64     // MID/NW: z_mid rows per WG
#define L2E    1.4426950408889634f

typedef _Float16 h2t __attribute__((ext_vector_type(2)));

__device__ __forceinline__ float fdot2u(uint32_t a, uint32_t b, float c) {
    return __builtin_amdgcn_fdot2(__builtin_bit_cast(h2t, a),
                                  __builtin_bit_cast(h2t, b), c, false);
}
__device__ __forceinline__ uint32_t packrtn(float a, float b) {
    h2t h = { (_Float16)a, (_Float16)b };
    return __builtin_bit_cast(uint32_t, h);
}
template <int CTRL>
__device__ __forceinline__ float dpp_add(float v) {
    int o = __builtin_amdgcn_update_dpp(0, __builtin_bit_cast(int, v), CTRL, 0xF, 0xF, true);
    return v + __builtin_bit_cast(float, o);
}
template <int CTRL>
__device__ __forceinline__ float dpp_get(float v) {   // fetch lane-permuted value
    int o = __builtin_amdgcn_update_dpp(0, __builtin_bit_cast(int, v), CTRL, 0xF, 0xF, true);
    return __builtin_bit_cast(float, o);
}
__device__ __forceinline__ float red16(float v) {     // sum over 16-lane DPP row
    v = dpp_add<0xB1>(v);   // quad_perm xor1
    v = dpp_add<0x4E>(v);   // quad_perm xor2
    v = dpp_add<0x124>(v);  // row_ror:4
    v = dpp_add<0x128>(v);  // row_ror:8
    return v;
}
__device__ __forceinline__ float sw_add16(float v) {  // += lane^16 value
    int o = __builtin_amdgcn_ds_swizzle(__builtin_bit_cast(int, v), 0x401F);
    return v + __builtin_bit_cast(float, o);
}
__device__ __forceinline__ float fexp2(float x) {
    float r;
    asm("v_exp_f32 %0, %1" : "=v"(r) : "v"(x));
    return r;
}
__device__ __forceinline__ float frcp(float x) { return __builtin_amdgcn_rcpf(x); }
__device__ __forceinline__ float fsigmoid(float x) { return frcp(1.f + fexp2(-x * L2E)); }
__device__ __forceinline__ float ftanh(float x) { return 1.f - 2.f * frcp(fexp2(x * (2.f * L2E)) + 1.f); }
// zin: 32 chunks x 17 u32, padded to 20 (80B, 16B-aligned chunk base)
__device__ __forceinline__ int zidx(int k) { return (k / 17) * 20 + (k % 17); }

// Stamped exchange: [BATCH][2(parity)][NW][HID] u64. hi32 = stamp (t+1),
// lo32 = packed fp16 (s-partial, m-partial). 8B atomic word => data is
// self-validating; relaxed suffices. Never reset (replay-safe: stale words
// from a previous replay are bit-identical; first call sees zero stamps).
__device__ uint64_t g_px[(size_t)BATCH * 2 * NW * HID];

// Round-8 structure (best-known: 1041us) with ONE fix: the x(t+1) prefetch
// is issued at LOOP TOP instead of between the drain and the polls. vmcnt
// retires in issue order, so a prefetch issued before the poll loads forced
// the poll's s_waitcnt to wait for the x load too (wave 0's finish was
// delayed by an HBM/LLC latency every step, dragging the whole WG through
// the final barrier). At loop top the x load hides under phase A+B and has
// retired by the drain; the poll's vmcnt waits are then clean.
__global__ __launch_bounds__(512, 1)
void metamu14_kernel(const float* __restrict__ x,      // [SEQ][BATCH][IN_]
                     const float* __restrict__ old_m,  // [BATCH][HID]
                     const float* __restrict__ old_s,  // [BATCH][HID]
                     const float* __restrict__ W_z,    // [MID][CONCAT]
                     const float* __restrict__ b_z,
                     const float* __restrict__ W_s,    // [HID][ZS]
                     const float* __restrict__ b_s,
                     const float* __restrict__ W_m,    // [HID][ZS]
                     const float* __restrict__ b_m,
                     float* __restrict__ out)
{
    const int bid = blockIdx.x;
    const int b   = bid & 63;      // batch
    const int w   = bid >> 6;      // weight quarter; {b, b+64, ...} same XCD
    const int tid = threadIdx.x;
    const int h   = tid;           // finish/px row (global h)

    __shared__ __align__(16) uint32_t zin2[2][32 * 20]; // [x|m|1/s] fp16 pairs
    __shared__ __align__(16) uint32_t zvec2[2][40];     // [x-slice(8)|z-quarter(32)]

    const int g2 = tid >> 5, c2 = tid & 31;   // phase A: 4-row group, K-chunk
    const int l  = tid & 1;                    // phase B: column-half

    // ---- one-time: weights -> VGPRs (fp16 RTN) ----
    uint32_t wA[4][17];
    #pragma unroll
    for (int r = 0; r < 4; ++r) {
        const float* p = W_z + (size_t)(QZ * w + 4 * g2 + r) * CONCAT + 34 * c2;
        #pragma unroll
        for (int i = 0; i < 17; ++i) {
            float2 a = *reinterpret_cast<const float2*>(p + 2 * i);
            wA[r][i] = packrtn(a.x, a.y);
        }
    }
    // phase-B: rows h0=tid&~1, h1=tid|1; col-half l of {x 16w..+16} U {z 64w..+64}
    uint32_t wS0[20], wM0[20], wS1[20], wM1[20];
    {
        const int h0 = tid & ~1, h1 = tid | 1;
        const float* ps0 = W_s + (size_t)h0 * ZS;
        const float* pm0 = W_m + (size_t)h0 * ZS;
        const float* ps1 = W_s + (size_t)h1 * ZS;
        const float* pm1 = W_m + (size_t)h1 * ZS;
        #pragma unroll
        for (int i = 0; i < 4; ++i) {   // x cols: 16w + 8l + 2i
            const int o = 16 * w + 8 * l + 2 * i;
            float2 a0 = *reinterpret_cast<const float2*>(ps0 + o);
            float2 b0 = *reinterpret_cast<const float2*>(pm0 + o);
            float2 a1 = *reinterpret_cast<const float2*>(ps1 + o);
            float2 b1 = *reinterpret_cast<const float2*>(pm1 + o);
            wS0[i] = packrtn(a0.x, a0.y); wM0[i] = packrtn(b0.x, b0.y);
            wS1[i] = packrtn(a1.x, a1.y); wM1[i] = packrtn(b1.x, b1.y);
        }
        #pragma unroll
        for (int i = 0; i < 16; ++i) {  // z cols: 64 + 64w + 32l + 2i
            const int o = 64 + 64 * w + 32 * l + 2 * i;
            float2 a0 = *reinterpret_cast<const float2*>(ps0 + o);
            float2 b0 = *reinterpret_cast<const float2*>(pm0 + o);
            float2 a1 = *reinterpret_cast<const float2*>(ps1 + o);
            float2 b1 = *reinterpret_cast<const float2*>(pm1 + o);
            wS0[4 + i] = packrtn(a0.x, a0.y); wM0[4 + i] = packrtn(b0.x, b0.y);
            wS1[4 + i] = packrtn(a1.x, a1.y); wM1[4 + i] = packrtn(b1.x, b1.y);
        }
    }
    float bz[4];
    #pragma unroll
    for (int r = 0; r < 4; ++r) bz[r] = b_z[QZ * w + 4 * g2 + r];
    const float bsv = b_s[h], bmv = b_m[h];

    // ---- registers: full per-h state (redundant across the 4 WGs) ----
    float sreg = old_s[b * HID + h];
    float mreg = old_m[b * HID + h];

    // x for t=0: threads 0..31 hold float pair (2*tid, 2*tid+1)
    float2 xv = {0.f, 0.f};
    if (tid < 32) xv = *reinterpret_cast<const float2*>(x + (size_t)b * IN_ + 2 * tid);

    // ---- initial staging of zin[0](t=0) and zvec[0] x-slice ----
    if (tid < 256) {
        float2 mv = *reinterpret_cast<const float2*>(old_m + b * HID + 2 * tid);
        zin2[0][zidx(32 + tid)] = packrtn(mv.x, mv.y);
    } else {
        const int j = tid - 256;
        float2 sv = *reinterpret_cast<const float2*>(old_s + b * HID + 2 * j);
        zin2[0][zidx(288 + j)] = packrtn(frcp(sv.x), frcp(sv.y));
    }
    if (tid < 32) zin2[0][zidx(tid)] = packrtn(xv.x, xv.y);
    if (tid >= 8 * w && tid < 8 * w + 8) zvec2[0][tid - 8 * w] = packrtn(xv.x, xv.y);
    __syncthreads();

    float* __restrict__ out_m = out;
    float* __restrict__ out_s = out + (size_t)SEQ * BATCH * HID;

    for (int t = 0; t < SEQ; ++t) {
        const int par = t & 1;
        const int np  = par ^ 1;
        const uint64_t want = (uint64_t)(t + 1);

        // x prefetch for t+1 at LOOP TOP: xv is dead here (consumed by the
        // previous staging); latency hides under phase A + barrier + phase B
        // and retires before the drain -> poll vmcnt waits stay clean.
        if (tid < 32 && t + 1 < SEQ)
            xv = *reinterpret_cast<const float2*>(
                x + ((size_t)(t + 1) * BATCH + b) * IN_ + 2 * tid);

        // ---- phase A: z_mid rows 4g2..4g2+3, K split over 32 lanes ----
        {
            uint32_t zf[17];
            const uint32_t* zc = &zin2[par][c2 * 20];
            #pragma unroll
            for (int i = 0; i < 4; ++i) {
                uint4 v = *reinterpret_cast<const uint4*>(zc + 4 * i);
                zf[4 * i] = v.x; zf[4 * i + 1] = v.y; zf[4 * i + 2] = v.z; zf[4 * i + 3] = v.w;
            }
            zf[16] = zc[16];
            float a0 = 0.f, a1 = 0.f, a2 = 0.f, a3 = 0.f;
            #pragma unroll
            for (int i = 0; i < 17; ++i) {
                a0 = fdot2u(wA[0][i], zf[i], a0);
                a1 = fdot2u(wA[1][i], zf[i], a1);
                a2 = fdot2u(wA[2][i], zf[i], a2);
                a3 = fdot2u(wA[3][i], zf[i], a3);
            }
            a0 = sw_add16(red16(a0));
            a1 = sw_add16(red16(a1));
            a2 = sw_add16(red16(a2));
            a3 = sw_add16(red16(a3));
            if (c2 == 0) {
                zvec2[par][8 + 2 * g2]     = packrtn(ftanh(a0 + bz[0]), ftanh(a1 + bz[1]));
                zvec2[par][8 + 2 * g2 + 1] = packrtn(ftanh(a2 + bz[2]), ftanh(a3 + bz[3]));
            }
        }
        __syncthreads();   // zvec z-quarter visible to phase B

        // ---- phase B: rows (tid&~1, tid|1) x col-half l; xor1 -> full sums ----
        float as, am;
        {
            uint32_t zg[20];
            {
                uint4 v = *reinterpret_cast<const uint4*>(&zvec2[par][4 * l]);
                zg[0] = v.x; zg[1] = v.y; zg[2] = v.z; zg[3] = v.w;
            }
            const uint32_t* zc2 = &zvec2[par][8 + 16 * l];
            #pragma unroll
            for (int i = 0; i < 4; ++i) {
                uint4 v = *reinterpret_cast<const uint4*>(zc2 + 4 * i);
                zg[4 + 4 * i] = v.x; zg[5 + 4 * i] = v.y; zg[6 + 4 * i] = v.z; zg[7 + 4 * i] = v.w;
            }
            float as0 = 0.f, am0 = 0.f, as1 = 0.f, am1 = 0.f;
            #pragma unroll
            for (int i = 0; i < 20; ++i) {
                as0 = fdot2u(wS0[i], zg[i], as0);
                am0 = fdot2u(wM0[i], zg[i], am0);
                as1 = fdot2u(wS1[i], zg[i], as1);
                am1 = fdot2u(wM1[i], zg[i], am1);
            }
            as0 = dpp_add<0xB1>(as0);   // + other column-half (lane^1)
            am0 = dpp_add<0xB1>(am0);
            as1 = dpp_add<0xB1>(as1);
            am1 = dpp_add<0xB1>(am1);
            as = l ? as1 : as0;          // full per-WG partial for row h = tid
            am = l ? am1 : am0;
        }
        // publish stamped word {t+1, packed partials}, then drain to the
        // coherence point BEFORE issuing any poll loads (per-thread). The
        // drain is load-bearing (round 12: removing it cost +64%); by now
        // the loop-top x load has retired, so the drain waits only on px.
        __hip_atomic_store(&g_px[(((size_t)b * 2 + par) * NW + w) * HID + h],
                           (want << 32) | (uint64_t)packrtn(as, am),
                           __ATOMIC_RELAXED, __HIP_MEMORY_SCOPE_AGENT);
        asm volatile("s_waitcnt vmcnt(0)" ::: "memory");

        // ---- poll 3 peers' stamped words CONCURRENTLY (sleep on retry) ----
        {
            const size_t base = ((size_t)b * 2 + par) * NW;
            const uint64_t* s0 = &g_px[(base + ((w + 1) & 3)) * HID + h];
            const uint64_t* s1 = &g_px[(base + ((w + 2) & 3)) * HID + h];
            const uint64_t* s2 = &g_px[(base + ((w + 3) & 3)) * HID + h];
            uint64_t p0 = __hip_atomic_load(s0, __ATOMIC_RELAXED, __HIP_MEMORY_SCOPE_AGENT);
            uint64_t p1 = __hip_atomic_load(s1, __ATOMIC_RELAXED, __HIP_MEMORY_SCOPE_AGENT);
            uint64_t p2 = __hip_atomic_load(s2, __ATOMIC_RELAXED, __HIP_MEMORY_SCOPE_AGENT);
            bool r0 = (p0 >> 32) == want;
            bool r1 = (p1 >> 32) == want;
            bool r2 = (p2 >> 32) == want;
            while (!(r0 && r1 && r2)) {
                __builtin_amdgcn_s_sleep(1);   // back off: don't starve stores
                if (!r0) { p0 = __hip_atomic_load(s0, __ATOMIC_RELAXED, __HIP_MEMORY_SCOPE_AGENT); }
                if (!r1) { p1 = __hip_atomic_load(s1, __ATOMIC_RELAXED, __HIP_MEMORY_SCOPE_AGENT); }
                if (!r2) { p2 = __hip_atomic_load(s2, __ATOMIC_RELAXED, __HIP_MEMORY_SCOPE_AGENT); }
                r0 = (p0 >> 32) == want;
                r1 = (p1 >> 32) == want;
                r2 = (p2 >> 32) == want;
            }
            h2t h0 = __builtin_bit_cast(h2t, (uint32_t)p0);
            h2t h1 = __builtin_bit_cast(h2t, (uint32_t)p1);
            h2t h2 = __builtin_bit_cast(h2t, (uint32_t)p2);
            as += (float)h0.x + (float)h1.x + (float)h2.x;
            am += (float)h0.y + (float)h1.y + (float)h2.y;
        }

        // ---- finish: state update for row h (redundant in all 4 WGs) ----
        const float sig  = fsigmoid(as + bsv);
        const float ns   = sreg + sig;
        const float inv  = frcp(ns);
        const float gate = sreg * inv;             // stop-grad: old_s / new_s
        const float nm   = gate * mreg + (1.f - gate) * ftanh(am + bmv);
        sreg = ns; mreg = nm;

        // owner WG writes output for its h-quarter
        if ((h >> 7) == w) {
            const size_t o = ((size_t)t * BATCH + b) * HID + h;
            out_m[o] = nm;
            out_s[o] = ns;
        }

        // ---- stage zin[np](t+1) + zvec[np] x-slice (DPP pair swap) ----
        const float nm_n  = dpp_get<0xB1>(nm);     // neighbor lane^1 value
        const float inv_n = dpp_get<0xB1>(inv);
        if ((tid & 1) == 0) {
            zin2[np][zidx(32 + (tid >> 1))]  = packrtn(nm, nm_n);
            zin2[np][zidx(288 + (tid >> 1))] = packrtn(inv, inv_n);
        }
        if (t + 1 < SEQ) {
            if (tid < 32) zin2[np][zidx(tid)] = packrtn(xv.x, xv.y);
            if (tid >= 8 * w && tid < 8 * w + 8)
                zvec2[np][tid - 8 * w] = packrtn(xv.x, xv.y);
        }
        __syncthreads();   // staging stable before next phase A
    }
}

extern "C" void kernel_launch(void* const* d_in, const int* in_sizes, int n_in,
                              void* d_out, int out_size, void* d_ws, size_t ws_size,
                              hipStream_t stream) {
    const float* x     = (const float*)d_in[0];
    const float* old_m = (const float*)d_in[1];
    const float* old_s = (const float*)d_in[2];
    const float* W_z   = (const float*)d_in[3];
    const float* b_z   = (const float*)d_in[4];
    const float* W_s   = (const float*)d_in[5];
    const float* b_s   = (const float*)d_in[6];
    const float* W_m   = (const float*)d_in[7];
    const float* b_m   = (const float*)d_in[8];

    metamu14_kernel<<<dim3(BATCH * NW), dim3(512), 0, stream>>>(
        x, old_m, old_s, W_z, b_z, W_s, b_s, W_m, b_m, (float*)d_out);
}

// Round 14
// 1041.469 us; speedup vs baseline: 1.6417x; 1.0681x over previous
//
#include <hip/hip_runtime.h>
#include <math.h>
#include <stdint.h>

#define SEQ    512
#define BATCH  64
#define IN_    64
#define HID    512
#define MID    256
#define CONCAT 1088
#define ZS     320
#define NW     4      // weight quarters (WGs per batch)
#define QZ     64     // MID/NW: z_mid rows per WG
#define L2E    1.4426950408889634f

typedef _Float16 h2t __attribute__((ext_vector_type(2)));

__device__ __forceinline__ float fdot2u(uint32_t a, uint32_t b, float c) {
    return __builtin_amdgcn_fdot2(__builtin_bit_cast(h2t, a),
                                  __builtin_bit_cast(h2t, b), c, false);
}
__device__ __forceinline__ uint32_t packrtn(float a, float b) {
    h2t h = { (_Float16)a, (_Float16)b };
    return __builtin_bit_cast(uint32_t, h);
}
template <int CTRL>
__device__ __forceinline__ float dpp_add(float v) {
    int o = __builtin_amdgcn_update_dpp(0, __builtin_bit_cast(int, v), CTRL, 0xF, 0xF, true);
    return v + __builtin_bit_cast(float, o);
}
template <int CTRL>
__device__ __forceinline__ float dpp_get(float v) {   // fetch lane-permuted value
    int o = __builtin_amdgcn_update_dpp(0, __builtin_bit_cast(int, v), CTRL, 0xF, 0xF, true);
    return __builtin_bit_cast(float, o);
}
__device__ __forceinline__ float red16(float v) {     // sum over 16-lane DPP row
    v = dpp_add<0xB1>(v);   // quad_perm xor1
    v = dpp_add<0x4E>(v);   // quad_perm xor2
    v = dpp_add<0x124>(v);  // row_ror:4
    v = dpp_add<0x128>(v);  // row_ror:8
    return v;
}
__device__ __forceinline__ float sw_add16(float v) {  // += lane^16 value
    int o = __builtin_amdgcn_ds_swizzle(__builtin_bit_cast(int, v), 0x401F);
    return v + __builtin_bit_cast(float, o);
}
// fast transcendentals: v_exp_f32 (2^x) + v_rcp_f32; ~1 ulp, saturation-safe
__device__ __forceinline__ float fexp2(float x) {
    float r;
    asm("v_exp_f32 %0, %1" : "=v"(r) : "v"(x));
    return r;
}
__device__ __forceinline__ float frcp(float x) { return __builtin_amdgcn_rcpf(x); }
__device__ __forceinline__ float fsigmoid(float x) {   // 1/(1+e^-x)
    return frcp(1.f + fexp2(-x * L2E));
}
__device__ __forceinline__ float ftanh(float x) {      // 1 - 2/(e^2x+1)
    return 1.f - 2.f * frcp(fexp2(x * (2.f * L2E)) + 1.f);
}
// zin: 32 chunks x 17 u32, padded to 20 (80B, 16B-aligned chunk base)
__device__ __forceinline__ int zidx(int k) { return (k / 17) * 20 + (k % 17); }

// Stamped exchange buffer: [BATCH][2(parity)][NW][HID] u64 words.
// hi32 = step stamp (t+1), lo32 = packed fp16 (s-partial, m-partial).
// Atomic 8B word => data self-validating; relaxed atomics suffice. Never
// reset: first call sees zero stamps; replays may read the previous replay's
// final-step word, which is bit-identical (kernel is deterministic).
__device__ uint64_t g_px[(size_t)BATCH * 2 * NW * HID];

// FINAL: round-8 structure verbatim (best measured: 1041 us). 4 WGs per
// batch; weights register-resident fp16 split 4 ways; one stamped-word LLC
// exchange per step (store -> per-thread vmcnt(0) drain -> 3 concurrent
// peer polls with s_sleep backoff); state finishing redundant in all 4 WGs;
// double-buffered LDS staging, 2 barriers/step. Perturbations measured and
// rejected: no-drain (+64%, round 12), loop-top prefetch (+7%, round 13),
// 2-batch stagger (+61%, round 11), 4-batch lockstep (+166%, round 9).
__global__ __launch_bounds__(512, 1)
void metamu_final_kernel(const float* __restrict__ x,      // [SEQ][BATCH][IN_]
                         const float* __restrict__ old_m,  // [BATCH][HID]
                         const float* __restrict__ old_s,  // [BATCH][HID]
                         const float* __restrict__ W_z,    // [MID][CONCAT]
                         const float* __restrict__ b_z,
                         const float* __restrict__ W_s,    // [HID][ZS]
                         const float* __restrict__ b_s,
                         const float* __restrict__ W_m,    // [HID][ZS]
                         const float* __restrict__ b_m,
                         float* __restrict__ out)
{
    const int bid = blockIdx.x;
    const int b   = bid & 63;      // batch
    const int w   = bid >> 6;      // weight quarter; {b, b+64, ...} same XCD
    const int tid = threadIdx.x;
    const int h   = tid;           // finish/px row (global h)

    __shared__ __align__(16) uint32_t zin2[2][32 * 20]; // [x|m|1/s] fp16 pairs
    __shared__ __align__(16) uint32_t zvec2[2][40];     // [x-slice(8)|z-quarter(32)]

    const int g2 = tid >> 5, c2 = tid & 31;   // phase A: 4-row group, K-chunk
    const int l  = tid & 1;                    // phase B: column-half

    // ---- one-time: weights -> VGPRs (fp16 RTN) ----
    uint32_t wA[4][17];
    #pragma unroll
    for (int r = 0; r < 4; ++r) {
        const float* p = W_z + (size_t)(QZ * w + 4 * g2 + r) * CONCAT + 34 * c2;
        #pragma unroll
        for (int i = 0; i < 17; ++i) {
            float2 a = *reinterpret_cast<const float2*>(p + 2 * i);
            wA[r][i] = packrtn(a.x, a.y);
        }
    }
    // phase-B: rows h0=tid&~1, h1=tid|1; col-half l of {x 16w..+16} U {z 64w..+64}
    uint32_t wS0[20], wM0[20], wS1[20], wM1[20];
    {
        const int h0 = tid & ~1, h1 = tid | 1;
        const float* ps0 = W_s + (size_t)h0 * ZS;
        const float* pm0 = W_m + (size_t)h0 * ZS;
        const float* ps1 = W_s + (size_t)h1 * ZS;
        const float* pm1 = W_m + (size_t)h1 * ZS;
        #pragma unroll
        for (int i = 0; i < 4; ++i) {   // x cols: 16w + 8l + 2i
            const int o = 16 * w + 8 * l + 2 * i;
            float2 a0 = *reinterpret_cast<const float2*>(ps0 + o);
            float2 b0 = *reinterpret_cast<const float2*>(pm0 + o);
            float2 a1 = *reinterpret_cast<const float2*>(ps1 + o);
            float2 b1 = *reinterpret_cast<const float2*>(pm1 + o);
            wS0[i] = packrtn(a0.x, a0.y); wM0[i] = packrtn(b0.x, b0.y);
            wS1[i] = packrtn(a1.x, a1.y); wM1[i] = packrtn(b1.x, b1.y);
        }
        #pragma unroll
        for (int i = 0; i < 16; ++i) {  // z cols: 64 + 64w + 32l + 2i
            const int o = 64 + 64 * w + 32 * l + 2 * i;
            float2 a0 = *reinterpret_cast<const float2*>(ps0 + o);
            float2 b0 = *reinterpret_cast<const float2*>(pm0 + o);
            float2 a1 = *reinterpret_cast<const float2*>(ps1 + o);
            float2 b1 = *reinterpret_cast<const float2*>(pm1 + o);
            wS0[4 + i] = packrtn(a0.x, a0.y); wM0[4 + i] = packrtn(b0.x, b0.y);
            wS1[4 + i] = packrtn(a1.x, a1.y); wM1[4 + i] = packrtn(b1.x, b1.y);
        }
    }
    float bz[4];
    #pragma unroll
    for (int r = 0; r < 4; ++r) bz[r] = b_z[QZ * w + 4 * g2 + r];
    const float bsv = b_s[h], bmv = b_m[h];

    // ---- registers: full per-h state (redundant across the 4 WGs) ----
    float sreg = old_s[b * HID + h];
    float mreg = old_m[b * HID + h];

    // x prefetch: threads 0..31 hold float pair (2*tid, 2*tid+1)
    float2 xv = {0.f, 0.f};
    if (tid < 32) xv = *reinterpret_cast<const float2*>(x + (size_t)b * IN_ + 2 * tid);

    // ---- initial staging of zin[0](t=0) and zvec[0] x-slice ----
    if (tid < 256) {
        float2 mv = *reinterpret_cast<const float2*>(old_m + b * HID + 2 * tid);
        zin2[0][zidx(32 + tid)] = packrtn(mv.x, mv.y);
    } else {
        const int j = tid - 256;
        float2 sv = *reinterpret_cast<const float2*>(old_s + b * HID + 2 * j);
        zin2[0][zidx(288 + j)] = packrtn(frcp(sv.x), frcp(sv.y));
    }
    if (tid < 32) zin2[0][zidx(tid)] = packrtn(xv.x, xv.y);
    if (tid >= 8 * w && tid < 8 * w + 8) zvec2[0][tid - 8 * w] = packrtn(xv.x, xv.y);
    __syncthreads();

    float* __restrict__ out_m = out;
    float* __restrict__ out_s = out + (size_t)SEQ * BATCH * HID;

    for (int t = 0; t < SEQ; ++t) {
        const int par = t & 1;
        const int np  = par ^ 1;
        const uint64_t want = (uint64_t)(t + 1);

        // ---- phase A: z_mid rows 4g2..4g2+3, K split over 32 lanes ----
        {
            uint32_t zf[17];
            const uint32_t* zc = &zin2[par][c2 * 20];
            #pragma unroll
            for (int i = 0; i < 4; ++i) {
                uint4 v = *reinterpret_cast<const uint4*>(zc + 4 * i);
                zf[4 * i] = v.x; zf[4 * i + 1] = v.y; zf[4 * i + 2] = v.z; zf[4 * i + 3] = v.w;
            }
            zf[16] = zc[16];
            float a0 = 0.f, a1 = 0.f, a2 = 0.f, a3 = 0.f;
            #pragma unroll
            for (int i = 0; i < 17; ++i) {
                a0 = fdot2u(wA[0][i], zf[i], a0);
                a1 = fdot2u(wA[1][i], zf[i], a1);
                a2 = fdot2u(wA[2][i], zf[i], a2);
                a3 = fdot2u(wA[3][i], zf[i], a3);
            }
            a0 = sw_add16(red16(a0));
            a1 = sw_add16(red16(a1));
            a2 = sw_add16(red16(a2));
            a3 = sw_add16(red16(a3));
            if (c2 == 0) {
                zvec2[par][8 + 2 * g2]     = packrtn(ftanh(a0 + bz[0]), ftanh(a1 + bz[1]));
                zvec2[par][8 + 2 * g2 + 1] = packrtn(ftanh(a2 + bz[2]), ftanh(a3 + bz[3]));
            }
        }
        __syncthreads();   // zvec z-quarter visible to phase B

        // ---- phase B: rows (tid&~1, tid|1) x col-half l; xor1 -> full sums ----
        float as, am;
        {
            uint32_t zg[20];
            {
                uint4 v = *reinterpret_cast<const uint4*>(&zvec2[par][4 * l]);
                zg[0] = v.x; zg[1] = v.y; zg[2] = v.z; zg[3] = v.w;
            }
            const uint32_t* zc2 = &zvec2[par][8 + 16 * l];
            #pragma unroll
            for (int i = 0; i < 4; ++i) {
                uint4 v = *reinterpret_cast<const uint4*>(zc2 + 4 * i);
                zg[4 + 4 * i] = v.x; zg[5 + 4 * i] = v.y; zg[6 + 4 * i] = v.z; zg[7 + 4 * i] = v.w;
            }
            float as0 = 0.f, am0 = 0.f, as1 = 0.f, am1 = 0.f;
            #pragma unroll
            for (int i = 0; i < 20; ++i) {
                as0 = fdot2u(wS0[i], zg[i], as0);
                am0 = fdot2u(wM0[i], zg[i], am0);
                as1 = fdot2u(wS1[i], zg[i], as1);
                am1 = fdot2u(wM1[i], zg[i], am1);
            }
            as0 = dpp_add<0xB1>(as0);   // + other column-half (lane^1)
            am0 = dpp_add<0xB1>(am0);
            as1 = dpp_add<0xB1>(as1);
            am1 = dpp_add<0xB1>(am1);
            as = l ? as1 : as0;          // full per-WG partial for row h = tid
            am = l ? am1 : am0;
        }
        // publish stamped word {t+1, packed partials}, then drain it to the
        // coherence point BEFORE issuing any poll loads (per-thread). The
        // drain is load-bearing: it rate-limits the poll storm so stores
        // aren't starved (round 12: removing it cost +64%).
        __hip_atomic_store(&g_px[(((size_t)b * 2 + par) * NW + w) * HID + h],
                           (want << 32) | (uint64_t)packrtn(as, am),
                           __ATOMIC_RELAXED, __HIP_MEMORY_SCOPE_AGENT);
        asm volatile("s_waitcnt vmcnt(0)" ::: "memory");

        // x prefetch for t+1: L2-hit (~200cy) retires before the LLC polls
        // (~400cy) under in-order vmcnt, so it is fully hidden here.
        if (tid < 32 && t + 1 < SEQ)
            xv = *reinterpret_cast<const float2*>(
                x + ((size_t)(t + 1) * BATCH + b) * IN_ + 2 * tid);

        // ---- poll 3 peers' stamped words CONCURRENTLY (sleep on retry) ----
        {
            const size_t base = ((size_t)b * 2 + par) * NW;
            const uint64_t* s0 = &g_px[(base + ((w + 1) & 3)) * HID + h];
            const uint64_t* s1 = &g_px[(base + ((w + 2) & 3)) * HID + h];
            const uint64_t* s2 = &g_px[(base + ((w + 3) & 3)) * HID + h];
            uint64_t p0 = __hip_atomic_load(s0, __ATOMIC_RELAXED, __HIP_MEMORY_SCOPE_AGENT);
            uint64_t p1 = __hip_atomic_load(s1, __ATOMIC_RELAXED, __HIP_MEMORY_SCOPE_AGENT);
            uint64_t p2 = __hip_atomic_load(s2, __ATOMIC_RELAXED, __HIP_MEMORY_SCOPE_AGENT);
            bool r0 = (p0 >> 32) == want;
            bool r1 = (p1 >> 32) == want;
            bool r2 = (p2 >> 32) == want;
            while (!(r0 && r1 && r2)) {
                __builtin_amdgcn_s_sleep(1);   // back off: don't starve stores
                if (!r0) { p0 = __hip_atomic_load(s0, __ATOMIC_RELAXED, __HIP_MEMORY_SCOPE_AGENT); }
                if (!r1) { p1 = __hip_atomic_load(s1, __ATOMIC_RELAXED, __HIP_MEMORY_SCOPE_AGENT); }
                if (!r2) { p2 = __hip_atomic_load(s2, __ATOMIC_RELAXED, __HIP_MEMORY_SCOPE_AGENT); }
                r0 = (p0 >> 32) == want;
                r1 = (p1 >> 32) == want;
                r2 = (p2 >> 32) == want;
            }
            h2t h0 = __builtin_bit_cast(h2t, (uint32_t)p0);
            h2t h1 = __builtin_bit_cast(h2t, (uint32_t)p1);
            h2t h2 = __builtin_bit_cast(h2t, (uint32_t)p2);
            as += (float)h0.x + (float)h1.x + (float)h2.x;
            am += (float)h0.y + (float)h1.y + (float)h2.y;
        }

        // ---- finish: state update for row h (redundant in all 4 WGs) ----
        const float sig  = fsigmoid(as + bsv);
        const float ns   = sreg + sig;
        const float inv  = frcp(ns);
        const float gate = sreg * inv;             // stop-grad: old_s / new_s
        const float nm   = gate * mreg + (1.f - gate) * ftanh(am + bmv);
        sreg = ns; mreg = nm;

        // owner WG writes output for its h-quarter
        if ((h >> 7) == w) {
            const size_t o = ((size_t)t * BATCH + b) * HID + h;
            out_m[o] = nm;
            out_s[o] = ns;
        }

        // ---- stage zin[np](t+1) + zvec[np] x-slice (DPP pair swap) ----
        const float nm_n  = dpp_get<0xB1>(nm);     // neighbor lane^1 value
        const float inv_n = dpp_get<0xB1>(inv);
        if ((tid & 1) == 0) {
            zin2[np][zidx(32 + (tid >> 1))]  = packrtn(nm, nm_n);
            zin2[np][zidx(288 + (tid >> 1))] = packrtn(inv, inv_n);
        }
        if (t + 1 < SEQ) {
            if (tid < 32) zin2[np][zidx(tid)] = packrtn(xv.x, xv.y);
            if (tid >= 8 * w && tid < 8 * w + 8)
                zvec2[np][tid - 8 * w] = packrtn(xv.x, xv.y);
        }
        __syncthreads();   // staging stable before next phase A
    }
}

extern "C" void kernel_launch(void* const* d_in, const int* in_sizes, int n_in,
                              void* d_out, int out_size, void* d_ws, size_t ws_size,
                              hipStream_t stream) {
    const float* x     = (const float*)d_in[0];
    const float* old_m = (const float*)d_in[1];
    const float* old_s = (const float*)d_in[2];
    const float* W_z   = (const float*)d_in[3];
    const float* b_z   = (const float*)d_in[4];
    const float* W_s   = (const float*)d_in[5];
    const float* b_s   = (const float*)d_in[6];
    const float* W_m   = (const float*)d_in[7];
    const float* b_m   = (const float*)d_in[8];

    metamu_final_kernel<<<dim3(BATCH * NW), dim3(512), 0, stream>>>(
        x, old_m, old_s, W_z, b_z, W_s, b_s, W_m, b_m, (float*)d_out);
}